// Round 1
// baseline (174.718 us; speedup 1.0000x reference)
//
#include <hip/hip_runtime.h>

// Maxwell viscoelastic recurrence as a blocked parallel scan.
//   gamma_{n+1} = (1 - 2*dt_n) * gamma_n + 2*dt_n * eps_n,  gamma_0 = 0
//   sig_n       = 2.5*eps_n - 2*gamma_n  (== E_INF*e + E*(e-gamma))
// Affine maps compose associatively -> per-thread local compose,
// wave shuffle scan, cross-wave LDS scan, then exact replay for sig.

constexpr int T_LEN     = 8192;
constexpr int THREADS   = 256;
constexpr int PER_THR   = T_LEN / THREADS;   // 32
constexpr int VEC       = PER_THR / 4;       // 8 float4 per array
constexpr float E_INF_C = 0.5f;
constexpr float E_C     = 2.0f;
constexpr float K_C     = 2.0f;              // E/ETA

__global__ __launch_bounds__(THREADS) void maxwell_scan_kernel(
    const float* __restrict__ eps, const float* __restrict__ dts,
    float* __restrict__ out)
{
    const int row  = blockIdx.x;
    const int tid  = threadIdx.x;
    const int lane = tid & 63;
    const int wave = tid >> 6;

    const long long base = (long long)row * T_LEN + (long long)tid * PER_THR;

    // ---- load 32 eps + 32 dts into registers (float4, lines fully consumed)
    float4 ev[VEC], dv[VEC];
    const float4* ep4 = reinterpret_cast<const float4*>(eps + base);
    const float4* dp4 = reinterpret_cast<const float4*>(dts + base);
#pragma unroll
    for (int j = 0; j < VEC; ++j) { ev[j] = ep4[j]; dv[j] = dp4[j]; }

    // ---- pass 1: local affine composition  gamma_out = a*gamma_in + b
    float a = 1.f, b = 0.f;
#pragma unroll
    for (int j = 0; j < VEC; ++j) {
        const float4 e = ev[j], d = dv[j];
        float an, bn;
        an = 1.f - K_C * d.x; bn = K_C * d.x * e.x; b = an * b + bn; a = an * a;
        an = 1.f - K_C * d.y; bn = K_C * d.y * e.y; b = an * b + bn; a = an * a;
        an = 1.f - K_C * d.z; bn = K_C * d.z * e.z; b = an * b + bn; a = an * a;
        an = 1.f - K_C * d.w; bn = K_C * d.w * e.w; b = an * b + bn; a = an * a;
    }

    // ---- wave-level inclusive scan of affine maps (compose later-after-earlier)
    float A = a, B = b;
#pragma unroll
    for (int off = 1; off < 64; off <<= 1) {
        float pA = __shfl_up(A, off, 64);
        float pB = __shfl_up(B, off, 64);
        if (lane >= off) { B = A * pB + B; A = A * pA; }
    }

    // ---- cross-wave scan (4 waves)
    __shared__ float wA[4], wB[4];
    __shared__ float incB[THREADS];
    if (lane == 63) { wA[wave] = A; wB[wave] = B; }
    __syncthreads();
    float pA = 1.f, pB = 0.f;                 // composition of waves [0, wave)
    for (int w = 0; w < wave; ++w) {          // apply wave w after current prefix
        pB = wA[w] * pB + wB[w];
        pA = wA[w] * pA;
    }
    // full inclusive map for this thread: g -> A*(pA*g + pB) + B
    incB[tid] = A * pB + B;
    __syncthreads();

    // gamma at this thread's chunk start = inclusive B of previous thread (gamma0=0)
    float gamma = (tid == 0) ? 0.f : incB[tid - 1];

    // ---- pass 2: exact replay of the reference recurrence, write sigma
    float4* op4 = reinterpret_cast<float4*>(out + base);
#pragma unroll
    for (int j = 0; j < VEC; ++j) {
        const float4 e = ev[j], d = dv[j];
        float4 s;
        { float df = e.x - gamma; s.x = E_INF_C * e.x + E_C * df; gamma += d.x * K_C * df; }
        { float df = e.y - gamma; s.y = E_INF_C * e.y + E_C * df; gamma += d.y * K_C * df; }
        { float df = e.z - gamma; s.z = E_INF_C * e.z + E_C * df; gamma += d.z * K_C * df; }
        { float df = e.w - gamma; s.w = E_INF_C * e.w + E_C * df; gamma += d.w * K_C * df; }
        op4[j] = s;
    }
}

extern "C" void kernel_launch(void* const* d_in, const int* in_sizes, int n_in,
                              void* d_out, int out_size, void* d_ws, size_t ws_size,
                              hipStream_t stream) {
    const float* eps = (const float*)d_in[0];
    const float* dts = (const float*)d_in[1];
    float* out = (float*)d_out;
    const int total = in_sizes[0];          // B * T
    const int nrows = total / T_LEN;        // 2048
    maxwell_scan_kernel<<<nrows, THREADS, 0, stream>>>(eps, dts, out);
}

// Round 5
// 171.300 us; speedup vs baseline: 1.0200x; 1.0200x over previous
//
#include <hip/hip_runtime.h>

// Maxwell viscoelastic recurrence as a blocked parallel scan.
//   gamma_{n+1} = (1 - 2*dt_n) * gamma_n + 2*dt_n * eps_n,  gamma_0 = 0
//   sig_n       = 2.5*eps_n - 2*gamma_n
// v2: 1024-thread blocks, 8 elems/thread -> values stay in VGPRs (16 regs),
// lane stride 32B (near-ideal line-request rate vs v1's 128B stride).

constexpr int T_LEN     = 8192;
constexpr int THREADS   = 1024;
constexpr int PER_THR   = T_LEN / THREADS;   // 8
constexpr int NWAVE     = THREADS / 64;      // 16
constexpr float E_INF_C = 0.5f;
constexpr float E_C     = 2.0f;
constexpr float K_C     = 2.0f;              // E/ETA

__global__ __launch_bounds__(THREADS) void maxwell_scan_kernel(
    const float* __restrict__ eps, const float* __restrict__ dts,
    float* __restrict__ out)
{
    const int row  = blockIdx.x;
    const int tid  = threadIdx.x;
    const int lane = tid & 63;
    const int wave = tid >> 6;

    const long long base = (long long)row * T_LEN + (long long)tid * PER_THR;

    // ---- load 8 eps + 8 dts into registers (4x float4, 32B lane stride)
    float4 ev[2], dv[2];
    const float4* ep4 = reinterpret_cast<const float4*>(eps + base);
    const float4* dp4 = reinterpret_cast<const float4*>(dts + base);
    ev[0] = ep4[0]; ev[1] = ep4[1];
    dv[0] = dp4[0]; dv[1] = dp4[1];

    // ---- pass 1: local affine composition  gamma_out = a*gamma_in + b
    float a = 1.f, b = 0.f;
#pragma unroll
    for (int j = 0; j < 2; ++j) {
        const float4 e = ev[j], d = dv[j];
        float an, t;
        t = K_C * d.x; an = 1.f - t; b = an * b + t * e.x; a = an * a;
        t = K_C * d.y; an = 1.f - t; b = an * b + t * e.y; a = an * a;
        t = K_C * d.z; an = 1.f - t; b = an * b + t * e.z; a = an * a;
        t = K_C * d.w; an = 1.f - t; b = an * b + t * e.w; a = an * a;
    }

    // ---- wave-level inclusive scan of affine maps
    float A = a, B = b;
#pragma unroll
    for (int off = 1; off < 64; off <<= 1) {
        float pA = __shfl_up(A, off, 64);
        float pB = __shfl_up(B, off, 64);
        if (lane >= off) { B = A * pB + B; A = A * pA; }
    }

    // ---- cross-wave scan (16 waves)
    __shared__ float wA[NWAVE], wB[NWAVE];
    __shared__ float incB[THREADS];
    if (lane == 63) { wA[wave] = A; wB[wave] = B; }
    __syncthreads();
    float pA = 1.f, pB = 0.f;                 // composition of waves [0, wave)
#pragma unroll 1
    for (int w = 0; w < wave; ++w) {          // LDS broadcast reads, 2 FMA each
        const float a_w = wA[w], b_w = wB[w];
        pB = a_w * pB + b_w;
        pA = a_w * pA;
    }
    // full inclusive B for this thread: gamma after its chunk (gamma0 = 0)
    incB[tid] = A * pB + B;
    __syncthreads();

    // gamma at this thread's chunk start = inclusive B of previous thread
    float gamma = (tid == 0) ? 0.f : incB[tid - 1];

    // ---- pass 2: exact replay of the reference recurrence, write sigma
    float4* op4 = reinterpret_cast<float4*>(out + base);
#pragma unroll
    for (int j = 0; j < 2; ++j) {
        const float4 e = ev[j], d = dv[j];
        float4 s;
        { float df = e.x - gamma; s.x = E_INF_C * e.x + E_C * df; gamma += d.x * K_C * df; }
        { float df = e.y - gamma; s.y = E_INF_C * e.y + E_C * df; gamma += d.y * K_C * df; }
        { float df = e.z - gamma; s.z = E_INF_C * e.z + E_C * df; gamma += d.z * K_C * df; }
        { float df = e.w - gamma; s.w = E_INF_C * e.w + E_C * df; gamma += d.w * K_C * df; }
        op4[j] = s;
    }
}

extern "C" void kernel_launch(void* const* d_in, const int* in_sizes, int n_in,
                              void* d_out, int out_size, void* d_ws, size_t ws_size,
                              hipStream_t stream) {
    const float* eps = (const float*)d_in[0];
    const float* dts = (const float*)d_in[1];
    float* out = (float*)d_out;
    const int total = in_sizes[0];          // B * T
    const int nrows = total / T_LEN;        // 2048
    maxwell_scan_kernel<<<nrows, THREADS, 0, stream>>>(eps, dts, out);
}